// Round 3
// baseline (29764.380 us; speedup 1.0000x reference)
//
#include <hip/hip_runtime.h>
#include <hip/hip_bf16.h>

#define BATCH 256
#define LAT 128
#define H 256
#define OUTD 64
#define SEQ 512

typedef short bf16x8 __attribute__((ext_vector_type(8)));
typedef float f32x4  __attribute__((ext_vector_type(4)));

__device__ __forceinline__ float sigm(float x)  { return 1.f / (1.f + __expf(-x)); }
__device__ __forceinline__ float tanhf_(float x){ return 1.f - 2.f / (__expf(2.f * x) + 1.f); }

__device__ __forceinline__ short f2bs(float x) {
    __hip_bfloat16 b = __float2bfloat16(x);
    return *reinterpret_cast<short*>(&b);
}
__device__ __forceinline__ bf16x8 pack8(const float* s) {
    bf16x8 v;
    v[0]=f2bs(s[0]); v[1]=f2bs(s[1]); v[2]=f2bs(s[2]); v[3]=f2bs(s[3]);
    v[4]=f2bs(s[4]); v[5]=f2bs(s[5]); v[6]=f2bs(s[6]); v[7]=f2bs(s[7]);
    return v;
}

// ---------------- Prologue 1: init h/c, x0, layer-1 bias vec, zero barriers ----------------
__global__ void lstm_prologue_init(const float* __restrict__ z,
                                   const float* __restrict__ Whid,
                                   const float* __restrict__ bhid,
                                   const float* __restrict__ Wcell,
                                   const float* __restrict__ bcell,
                                   const float* __restrict__ Win,
                                   const float* __restrict__ bin,
                                   const float* __restrict__ bih1,
                                   const float* __restrict__ bhh1,
                                   __hip_bfloat16* __restrict__ h0init,
                                   __hip_bfloat16* __restrict__ h1init,
                                   float* __restrict__ c0,
                                   float* __restrict__ c1,
                                   float* __restrict__ x0,
                                   float* __restrict__ gxb1,
                                   unsigned* __restrict__ bar)
{
    int t = blockIdx.x * 256 + threadIdx.x;
    if (t < 131072) {                    // hidden init: [256 x 512]
        int b = t >> 9, col = t & 511;
        const float* w  = Whid + col * LAT;
        const float* zr = z + b * LAT;
        float acc = bhid[col];
        for (int k = 0; k < LAT; k++) acc += zr[k] * w[k];
        if (col < H) h0init[b * H + col] = __float2bfloat16(acc);
        else         h1init[b * H + (col - H)] = __float2bfloat16(acc);
    } else if (t < 262144) {             // cell init: [256 x 512]
        int tt = t - 131072;
        int b = tt >> 9, col = tt & 511;
        const float* w  = Wcell + col * LAT;
        const float* zr = z + b * LAT;
        float acc = bcell[col];
        for (int k = 0; k < LAT; k++) acc += zr[k] * w[k];
        if (col < H) c0[b * H + col] = acc;
        else         c1[b * H + (col - H)] = acc;
    } else if (t < 327680) {             // x0 = z @ fc_input_w.T + b : [256 x 256]
        int tt = t - 262144;
        int b = tt >> 8, j = tt & 255;
        const float* w  = Win + j * LAT;
        const float* zr = z + b * LAT;
        float acc = bin[j];
        for (int k = 0; k < LAT; k++) acc += zr[k] * w[k];
        x0[b * H + j] = acc;
    } else if (t < 328704) {             // layer-1 gate bias vector [1024]
        int g = t - 327680;
        gxb1[g] = bih1[g] + bhh1[g];
    } else if (t < 329728) {             // zero cluster-barrier state
        bar[t - 328704] = 0u;
    }
}

// ---------------- Prologue 2: gx0 = x0 @ W_ih0.T + b_ih0 + b_hh0  [256 x 1024] ----------------
__global__ void lstm_prologue_gx0(const float* __restrict__ x0,
                                  const float* __restrict__ Wih0,
                                  const float* __restrict__ bih0,
                                  const float* __restrict__ bhh0,
                                  float* __restrict__ gxb0)
{
    __shared__ float xs[H];
    int b = blockIdx.y;
    int n = blockIdx.x * 256 + threadIdx.x;
    xs[threadIdx.x] = x0[b * H + threadIdx.x];
    __syncthreads();
    const float* w = Wih0 + n * H;
    float acc = bih0[n] + bhh0[n];
    for (int k = 0; k < H; k++) acc += xs[k] * w[k];
    gxb0[b * 4 * H + n] = acc;
}

// ---------------- Persistent kernel ----------------
// 256 wgs of 256 threads, 1/CU (cooperative). wg = bg*16 + j.
// Cluster bg = 16 wgs handling batch rows [16bg,16bg+16); wg j owns hidden
// cols [16j,16j+16) of both layers; wgs j<4 also own out cols [16j,16j+16).
// Weight B-fragments register-resident; h exchanged via global + cluster barrier.
__global__ __launch_bounds__(256, 1)
void lstm_persistent(const float* __restrict__ gxb0, const float* __restrict__ gxb1,
                     const float* __restrict__ c0g, const float* __restrict__ c1g,
                     __hip_bfloat16* __restrict__ h0b0, __hip_bfloat16* __restrict__ h0b1,
                     __hip_bfloat16* __restrict__ h1b0, __hip_bfloat16* __restrict__ h1b1,
                     const float* __restrict__ Whh0, const float* __restrict__ Wih1,
                     const float* __restrict__ Whh1, const float* __restrict__ Wout,
                     const float* __restrict__ bout, float* __restrict__ out,
                     unsigned* __restrict__ bar)
{
    const int wg = blockIdx.x;
    const int bg = wg >> 4;
    const int j  = wg & 15;
    const int colbase = j * 16;
    const int tid  = threadIdx.x;
    const int wave = tid >> 6;          // gate index for L0/L1
    const int lane = tid & 63;
    const int q  = lane >> 4;
    const int ln = lane & 15;
    const int m_ = tid >> 4, n_ = tid & 15;

    __shared__ __hip_bfloat16 hs0[16 * 264];   // h0_prev stage, +8 pad per row
    __shared__ __hip_bfloat16 hs1[16 * 264];   // h1_prev stage
    __shared__ float sm[4][16][17];            // gate exchange
    __shared__ float gx0s[4][16][17];          // L0 input-proj slice (constant)
    __shared__ float gx1s[4][17];              // L1 bias slice (constant)

    // ---- register-resident weight B-fragments ----
    bf16x8 wf[3][8];
    {
        const float* mats[3] = { Whh0, Wih1, Whh1 };
        const int row = wave * H + colbase + ln;
        #pragma unroll
        for (int mm = 0; mm < 3; mm++) {
            const float* src = mats[mm] + row * H + q * 8;
            #pragma unroll
            for (int kk = 0; kk < 8; kk++) wf[mm][kk] = pack8(src + kk * 32);
        }
    }
    const bool doOut = (j < 4) && (wave == 0);
    bf16x8 wo[8];
    float bo = 0.f;
    if (doOut) {
        const int orow = j * 16 + ln;
        const float* src = Wout + orow * H + q * 8;
        #pragma unroll
        for (int kk = 0; kk < 8; kk++) wo[kk] = pack8(src + kk * 32);
        bo = bout[orow];
    }

    // ---- constant LDS preloads ----
    #pragma unroll
    for (int g = 0; g < 4; g++)
        gx0s[g][m_][n_] = gxb0[(bg * 16 + m_) * 1024 + g * H + colbase + n_];
    if (tid < 64) gx1s[tid >> 4][tid & 15] = gxb1[(tid >> 4) * H + colbase + (tid & 15)];

    // ---- cell state in registers ----
    const int bidx = (bg * 16 + m_) * H + colbase + n_;
    float creg0 = c0g[bidx];
    float creg1 = c1g[bidx];

    unsigned* cnt = bar + bg * 64;
    unsigned* gen = bar + bg * 64 + 32;

    for (int k = 0; k <= SEQ + 1; k++) {
        __hip_bfloat16* h0p = (k & 1) ? h0b0 : h0b1;
        __hip_bfloat16* h0c = (k & 1) ? h0b1 : h0b0;
        __hip_bfloat16* h1p = (k & 1) ? h1b1 : h1b0;
        __hip_bfloat16* h1c = (k & 1) ? h1b0 : h1b1;

        // stage h0_prev, h1_prev (full bg slice) into LDS
        {
            const int r = tid >> 4, cb = (tid & 15) * 16;
            const __hip_bfloat16* s0 = h0p + (bg * 16 + r) * H + cb;
            const __hip_bfloat16* s1 = h1p + (bg * 16 + r) * H + cb;
            *(bf16x8*)&hs0[r * 264 + cb]     = *(const bf16x8*)(s0);
            *(bf16x8*)&hs0[r * 264 + cb + 8] = *(const bf16x8*)(s0 + 8);
            *(bf16x8*)&hs1[r * 264 + cb]     = *(const bf16x8*)(s1);
            *(bf16x8*)&hs1[r * 264 + cb + 8] = *(const bf16x8*)(s1 + 8);
        }
        __syncthreads();

        // A-fragments (shared by L0, L1, out)
        bf16x8 ha0[8], ha1[8];
        #pragma unroll
        for (int kk = 0; kk < 8; kk++) {
            ha0[kk] = *(const bf16x8*)&hs0[ln * 264 + kk * 32 + q * 8];
            ha1[kk] = *(const bf16x8*)&hs1[ln * 264 + kk * 32 + q * 8];
        }

        // ---- layer 0, step k ----
        if (k < SEQ) {
            f32x4 acc = {0.f, 0.f, 0.f, 0.f};
            #pragma unroll
            for (int kk = 0; kk < 8; kk++)
                acc = __builtin_amdgcn_mfma_f32_16x16x32_bf16(ha0[kk], wf[0][kk], acc, 0, 0, 0);
            #pragma unroll
            for (int r = 0; r < 4; r++)
                sm[wave][q * 4 + r][ln] = acc[r] + gx0s[wave][q * 4 + r][ln];
        }
        __syncthreads();
        if (k < SEQ) {
            float xi = sm[0][m_][n_], xf = sm[1][m_][n_], xg = sm[2][m_][n_], xo = sm[3][m_][n_];
            float c = sigm(xf) * creg0 + sigm(xi) * tanhf_(xg);
            creg0 = c;
            h0c[bidx] = __float2bfloat16(sigm(xo) * tanhf_(c));
        }
        __syncthreads();   // guard sm reuse

        // ---- layer 1, step k-1 ----
        if (k >= 1 && k <= SEQ) {
            f32x4 acc = {0.f, 0.f, 0.f, 0.f};
            #pragma unroll
            for (int kk = 0; kk < 8; kk++)
                acc = __builtin_amdgcn_mfma_f32_16x16x32_bf16(ha0[kk], wf[1][kk], acc, 0, 0, 0);
            #pragma unroll
            for (int kk = 0; kk < 8; kk++)
                acc = __builtin_amdgcn_mfma_f32_16x16x32_bf16(ha1[kk], wf[2][kk], acc, 0, 0, 0);
            #pragma unroll
            for (int r = 0; r < 4; r++)
                sm[wave][q * 4 + r][ln] = acc[r] + gx1s[wave][ln];
        }
        __syncthreads();
        if (k >= 1 && k <= SEQ) {
            float xi = sm[0][m_][n_], xf = sm[1][m_][n_], xg = sm[2][m_][n_], xo = sm[3][m_][n_];
            float c = sigm(xf) * creg1 + sigm(xi) * tanhf_(xg);
            creg1 = c;
            h1c[bidx] = __float2bfloat16(sigm(xo) * tanhf_(c));
        }

        // ---- output projection, step k-2 (reuses ha1 = h1_{k-2}) ----
        if (k >= 2 && doOut) {
            f32x4 acc = {0.f, 0.f, 0.f, 0.f};
            #pragma unroll
            for (int kk = 0; kk < 8; kk++)
                acc = __builtin_amdgcn_mfma_f32_16x16x32_bf16(ha1[kk], wo[kk], acc, 0, 0, 0);
            const int t = k - 2;
            #pragma unroll
            for (int r = 0; r < 4; r++)
                out[(bg * 16 + q * 4 + r) * (SEQ * OUTD) + t * OUTD + j * 16 + ln] = acc[r] + bo;
        }

        // ---- cluster barrier (16 wgs, device-scope) ----
        if (k < SEQ + 1) {
            __threadfence();            // release h stores
            __syncthreads();
            if (tid == 0) {
                unsigned g = __hip_atomic_load(gen, __ATOMIC_RELAXED, __HIP_MEMORY_SCOPE_AGENT);
                unsigned arrived = __hip_atomic_fetch_add(cnt, 1u, __ATOMIC_ACQ_REL, __HIP_MEMORY_SCOPE_AGENT);
                if (arrived == 15u) {
                    __hip_atomic_store(cnt, 0u, __ATOMIC_RELAXED, __HIP_MEMORY_SCOPE_AGENT);
                    __hip_atomic_fetch_add(gen, 1u, __ATOMIC_RELEASE, __HIP_MEMORY_SCOPE_AGENT);
                } else {
                    while (__hip_atomic_load(gen, __ATOMIC_ACQUIRE, __HIP_MEMORY_SCOPE_AGENT) == g) { }
                }
            }
            __syncthreads();
            __threadfence();            // acquire: fresh view of peer h stores
        }
    }
}

extern "C" void kernel_launch(void* const* d_in, const int* in_sizes, int n_in,
                              void* d_out, int out_size, void* d_ws, size_t ws_size,
                              hipStream_t stream) {
    const float* z     = (const float*)d_in[0];
    const float* Whid  = (const float*)d_in[1];
    const float* bhid  = (const float*)d_in[2];
    const float* Wcell = (const float*)d_in[3];
    const float* bcell = (const float*)d_in[4];
    const float* Win   = (const float*)d_in[5];
    const float* bin   = (const float*)d_in[6];
    const float* Wih0  = (const float*)d_in[7];
    const float* Whh0  = (const float*)d_in[8];
    const float* bih0  = (const float*)d_in[9];
    const float* bhh0  = (const float*)d_in[10];
    const float* Wih1  = (const float*)d_in[11];
    const float* Whh1  = (const float*)d_in[12];
    const float* bih1  = (const float*)d_in[13];
    const float* bhh1  = (const float*)d_in[14];
    const float* Wout  = (const float*)d_in[15];
    const float* bout  = (const float*)d_in[16];
    float* out = (float*)d_out;

    // workspace carve-up (~2.4 MB)
    float* gxb0 = (float*)d_ws;                  // [256][1024]
    float* gxb1 = gxb0 + 262144;                 // [1024]
    float* c0   = gxb1 + 1024;                   // [256][256]
    float* c1   = c0 + 65536;                    // [256][256]
    float* x0   = c1 + 65536;                    // [256][256]
    __hip_bfloat16* h0b0 = (__hip_bfloat16*)(x0 + 65536);   // [256][256] bf16 x4 buffers
    __hip_bfloat16* h0b1 = h0b0 + 65536;
    __hip_bfloat16* h1b0 = h0b1 + 65536;
    __hip_bfloat16* h1b1 = h1b0 + 65536;
    unsigned* bar = (unsigned*)(h1b1 + 65536);   // [1024] cluster barrier state

    lstm_prologue_init<<<1288, 256, 0, stream>>>(z, Whid, bhid, Wcell, bcell, Win, bin,
                                                 bih1, bhh1, h0b1, h1b1, c0, c1, x0, gxb1, bar);
    lstm_prologue_gx0<<<dim3(4, 256), 256, 0, stream>>>(x0, Wih0, bih0, bhh0, gxb0);

    void* kargs[] = { (void*)&gxb0, (void*)&gxb1, (void*)&c0, (void*)&c1,
                      (void*)&h0b0, (void*)&h0b1, (void*)&h1b0, (void*)&h1b1,
                      (void*)&Whh0, (void*)&Wih1, (void*)&Whh1, (void*)&Wout,
                      (void*)&bout, (void*)&out, (void*)&bar };
    hipLaunchCooperativeKernel((const void*)lstm_persistent, dim3(256), dim3(256),
                               kargs, 0, stream);
}

// Round 5
// 2350.469 us; speedup vs baseline: 12.6632x; 12.6632x over previous
//
#include <hip/hip_runtime.h>
#include <hip/hip_bf16.h>

#define BATCH 256
#define LAT 128
#define H 256
#define OUTD 64
#define SEQ 512

typedef short bf16x8 __attribute__((ext_vector_type(8)));
typedef float f32x4  __attribute__((ext_vector_type(4)));
typedef unsigned long long u64;

__device__ __forceinline__ float sigm(float x)  { return 1.f / (1.f + __expf(-x)); }
__device__ __forceinline__ float tanhf_(float x){ return 1.f - 2.f / (__expf(2.f * x) + 1.f); }

__device__ __forceinline__ short f2bs(float x) {
    __hip_bfloat16 b = __float2bfloat16(x);
    return *reinterpret_cast<short*>(&b);
}
__device__ __forceinline__ bf16x8 pack8(const float* s) {
    bf16x8 v;
    v[0]=f2bs(s[0]); v[1]=f2bs(s[1]); v[2]=f2bs(s[2]); v[3]=f2bs(s[3]);
    v[4]=f2bs(s[4]); v[5]=f2bs(s[5]); v[6]=f2bs(s[6]); v[7]=f2bs(s[7]);
    return v;
}

// ---- LLC-direct (coherent, fence-free) accessors: lower to global_load/store sc0 sc1 ----
__device__ __forceinline__ u64 sys_load_u64(const u64* p) {
    return __hip_atomic_load(p, __ATOMIC_RELAXED, __HIP_MEMORY_SCOPE_SYSTEM);
}
__device__ __forceinline__ void sys_store_u64(u64* p, u64 v) {
    __hip_atomic_store(p, v, __ATOMIC_RELAXED, __HIP_MEMORY_SCOPE_SYSTEM);
}
__device__ __forceinline__ unsigned sys_load_u32(const unsigned* p) {
    return __hip_atomic_load(p, __ATOMIC_RELAXED, __HIP_MEMORY_SCOPE_SYSTEM);
}
__device__ __forceinline__ void sys_store_u32(unsigned* p, unsigned v) {
    __hip_atomic_store(p, v, __ATOMIC_RELAXED, __HIP_MEMORY_SCOPE_SYSTEM);
}

// ---------------- Prologue 1: init h/c, x0, layer-1 bias vec, zero barrier flags ----------------
__global__ void lstm_prologue_init(const float* __restrict__ z,
                                   const float* __restrict__ Whid,
                                   const float* __restrict__ bhid,
                                   const float* __restrict__ Wcell,
                                   const float* __restrict__ bcell,
                                   const float* __restrict__ Win,
                                   const float* __restrict__ bin,
                                   const float* __restrict__ bih1,
                                   const float* __restrict__ bhh1,
                                   __hip_bfloat16* __restrict__ h0init,
                                   __hip_bfloat16* __restrict__ h1init,
                                   float* __restrict__ c0,
                                   float* __restrict__ c1,
                                   float* __restrict__ x0,
                                   float* __restrict__ gxb1,
                                   unsigned* __restrict__ bar)
{
    int t = blockIdx.x * 256 + threadIdx.x;
    if (t < 131072) {                    // hidden init: [256 x 512]
        int b = t >> 9, col = t & 511;
        const float* w  = Whid + col * LAT;
        const float* zr = z + b * LAT;
        float acc = bhid[col];
        for (int k = 0; k < LAT; k++) acc += zr[k] * w[k];
        if (col < H) h0init[b * H + col] = __float2bfloat16(acc);
        else         h1init[b * H + (col - H)] = __float2bfloat16(acc);
    } else if (t < 262144) {             // cell init: [256 x 512]
        int tt = t - 131072;
        int b = tt >> 9, col = tt & 511;
        const float* w  = Wcell + col * LAT;
        const float* zr = z + b * LAT;
        float acc = bcell[col];
        for (int k = 0; k < LAT; k++) acc += zr[k] * w[k];
        if (col < H) c0[b * H + col] = acc;
        else         c1[b * H + (col - H)] = acc;
    } else if (t < 327680) {             // x0 = z @ fc_input_w.T + b : [256 x 256]
        int tt = t - 262144;
        int b = tt >> 8, j = tt & 255;
        const float* w  = Win + j * LAT;
        const float* zr = z + b * LAT;
        float acc = bin[j];
        for (int k = 0; k < LAT; k++) acc += zr[k] * w[k];
        x0[b * H + j] = acc;
    } else if (t < 328704) {             // layer-1 gate bias vector [1024]
        int g = t - 327680;
        gxb1[g] = bih1[g] + bhh1[g];
    } else if (t < 332800) {             // zero barrier flags [4096]
        bar[t - 328704] = 0u;
    }
}

// ---------------- Prologue 2: gx0 = x0 @ W_ih0.T + b_ih0 + b_hh0  [256 x 1024] ----------------
__global__ void lstm_prologue_gx0(const float* __restrict__ x0,
                                  const float* __restrict__ Wih0,
                                  const float* __restrict__ bih0,
                                  const float* __restrict__ bhh0,
                                  float* __restrict__ gxb0)
{
    __shared__ float xs[H];
    int b = blockIdx.y;
    int n = blockIdx.x * 256 + threadIdx.x;
    xs[threadIdx.x] = x0[b * H + threadIdx.x];
    __syncthreads();
    const float* w = Wih0 + n * H;
    float acc = bih0[n] + bhh0[n];
    for (int k = 0; k < H; k++) acc += xs[k] * w[k];
    gxb0[b * 4 * H + n] = acc;
}

// ---------------- Persistent kernel ----------------
// 256 wgs x 256 thr, cooperative. Cluster bg = 16 wgs, batch rows [16bg,16bg+16);
// wg j owns gate cols [16j,16j+16). Weights in VGPRs, c in regs, gx in LDS.
// All cross-wg traffic = SYSTEM-scope RELAXED atomics (LLC-direct, NO fences,
// NO L2 inv/wb). Barrier = monotone per-wg step flags, 64 B apart.
// Publish guards: ho0 valid only for k<SEQ, ho1 only for k>=1 (k=0 clobbered
// the h1 init buffer in round 4 — fatal).
__global__ __launch_bounds__(256, 1)
void lstm_persistent(const float* __restrict__ gxb0, const float* __restrict__ gxb1,
                     const float* __restrict__ c0g, const float* __restrict__ c1g,
                     u64* __restrict__ h0b0, u64* __restrict__ h0b1,
                     u64* __restrict__ h1b0, u64* __restrict__ h1b1,
                     const float* __restrict__ Whh0, const float* __restrict__ Wih1,
                     const float* __restrict__ Whh1, const float* __restrict__ Wout,
                     const float* __restrict__ bout, float* __restrict__ out,
                     unsigned* __restrict__ bar)
{
    const int wg = blockIdx.x;
    const int bg = wg >> 4;
    const int j  = wg & 15;
    const int colbase = j * 16;
    const int tid  = threadIdx.x;
    const int wave = tid >> 6;
    const int lane = tid & 63;
    const int q  = lane >> 4;
    const int ln = lane & 15;
    const int m_ = tid >> 4, n_ = tid & 15;

    __shared__ u64 hs0[16 * 66];               // h0_prev stage: 16 rows x 264 shorts
    __shared__ u64 hs1[16 * 66];               // h1_prev stage
    __shared__ float sm[4][16][17];            // gate exchange
    __shared__ float gx0s[4][16][17];          // L0 input-proj slice (constant)
    __shared__ float gx1s[4][17];              // L1 bias slice (constant)
    __shared__ short ho0[16][20];              // h0 output tile (pack staging)
    __shared__ short ho1[16][20];              // h1 output tile

    // ---- register-resident weight B-fragments ----
    bf16x8 wf[3][8];
    {
        const float* mats[3] = { Whh0, Wih1, Whh1 };
        const int row = wave * H + colbase + ln;
        #pragma unroll
        for (int mm = 0; mm < 3; mm++) {
            const float* src = mats[mm] + row * H + q * 8;
            #pragma unroll
            for (int kk = 0; kk < 8; kk++) wf[mm][kk] = pack8(src + kk * 32);
        }
    }
    const bool doOut = (j < 4) && (wave == 0);
    bf16x8 wo[8];
    float bo = 0.f;
    if (doOut) {
        const int orow = j * 16 + ln;
        const float* src = Wout + orow * H + q * 8;
        #pragma unroll
        for (int kk = 0; kk < 8; kk++) wo[kk] = pack8(src + kk * 32);
        bo = bout[orow];
    }

    // ---- constant LDS preloads ----
    #pragma unroll
    for (int g = 0; g < 4; g++)
        gx0s[g][m_][n_] = gxb0[(bg * 16 + m_) * 1024 + g * H + colbase + n_];
    if (tid < 64) gx1s[tid >> 4][tid & 15] = gxb1[(tid >> 4) * H + colbase + (tid & 15)];

    // ---- cell state in registers ----
    const int bidx = (bg * 16 + m_) * H + colbase + n_;
    float creg0 = c0g[bidx];
    float creg1 = c1g[bidx];

    unsigned* flags = bar + bg * 256;          // 16 flags, 64 B apart

    const short* hp0 = (const short*)hs0;
    const short* hp1 = (const short*)hs1;

    for (int k = 0; k <= SEQ + 1; k++) {
        u64* h0p = (k & 1) ? h0b0 : h0b1;
        u64* h0c = (k & 1) ? h0b1 : h0b0;
        u64* h1p = (k & 1) ? h1b1 : h1b0;
        u64* h1c = (k & 1) ? h1b0 : h1b1;

        // ---- wait for cluster peers to finish step k-1 ----
        if (k > 0) {
            if (tid < 16) {
                while (sys_load_u32(&flags[tid * 16]) < (unsigned)k) { }
            }
        }
        __syncthreads();

        // ---- stage h0_prev, h1_prev (full bg row-slice) into LDS via LLC loads ----
        {
            const u64* r0 = h0p + bg * 16 * 64;      // 256 bf16 = 64 u64 per row
            const u64* r1 = h1p + bg * 16 * 64;
            #pragma unroll
            for (int i = 0; i < 4; i++) {
                int flat = i * 256 + tid;            // [0,1024): 16 rows x 64 u64
                int row = flat >> 6, c8 = flat & 63;
                hs0[row * 66 + c8] = sys_load_u64(r0 + row * 64 + c8);
                hs1[row * 66 + c8] = sys_load_u64(r1 + row * 64 + c8);
            }
        }
        __syncthreads();

        // ---- A-fragments (shared by L0, L1, out) ----
        bf16x8 ha0[8], ha1[8];
        #pragma unroll
        for (int kk = 0; kk < 8; kk++) {
            ha0[kk] = *(const bf16x8*)&hp0[ln * 264 + kk * 32 + q * 8];
            ha1[kk] = *(const bf16x8*)&hp1[ln * 264 + kk * 32 + q * 8];
        }

        // ---- layer 0, step k ----
        if (k < SEQ) {
            f32x4 acc = {0.f, 0.f, 0.f, 0.f};
            #pragma unroll
            for (int kk = 0; kk < 8; kk++)
                acc = __builtin_amdgcn_mfma_f32_16x16x32_bf16(ha0[kk], wf[0][kk], acc, 0, 0, 0);
            #pragma unroll
            for (int r = 0; r < 4; r++)
                sm[wave][q * 4 + r][ln] = acc[r] + gx0s[wave][q * 4 + r][ln];
        }
        __syncthreads();
        if (k < SEQ) {
            float xi = sm[0][m_][n_], xf = sm[1][m_][n_], xg = sm[2][m_][n_], xo = sm[3][m_][n_];
            float c = sigm(xf) * creg0 + sigm(xi) * tanhf_(xg);
            creg0 = c;
            ho0[m_][n_] = f2bs(sigm(xo) * tanhf_(c));
        }
        __syncthreads();   // guard sm reuse

        // ---- layer 1, step k-1 ----
        if (k >= 1 && k <= SEQ) {
            f32x4 acc = {0.f, 0.f, 0.f, 0.f};
            #pragma unroll
            for (int kk = 0; kk < 8; kk++)
                acc = __builtin_amdgcn_mfma_f32_16x16x32_bf16(ha0[kk], wf[1][kk], acc, 0, 0, 0);
            #pragma unroll
            for (int kk = 0; kk < 8; kk++)
                acc = __builtin_amdgcn_mfma_f32_16x16x32_bf16(ha1[kk], wf[2][kk], acc, 0, 0, 0);
            #pragma unroll
            for (int r = 0; r < 4; r++)
                sm[wave][q * 4 + r][ln] = acc[r] + gx1s[wave][ln];
        }
        __syncthreads();
        if (k >= 1 && k <= SEQ) {
            float xi = sm[0][m_][n_], xf = sm[1][m_][n_], xg = sm[2][m_][n_], xo = sm[3][m_][n_];
            float c = sigm(xf) * creg1 + sigm(xi) * tanhf_(xg);
            creg1 = c;
            ho1[m_][n_] = f2bs(sigm(xo) * tanhf_(c));
        }

        // ---- output projection, step k-2 (reuses ha1 = h1_{k-2}) ----
        if (k >= 2 && doOut) {
            f32x4 acc = {0.f, 0.f, 0.f, 0.f};
            #pragma unroll
            for (int kk = 0; kk < 8; kk++)
                acc = __builtin_amdgcn_mfma_f32_16x16x32_bf16(ha1[kk], wo[kk], acc, 0, 0, 0);
            const int t = k - 2;
            #pragma unroll
            for (int r = 0; r < 4; r++)
                out[(bg * 16 + q * 4 + r) * (SEQ * OUTD) + t * OUTD + j * 16 + ln] = acc[r] + bo;
        }
        __syncthreads();   // ho0/ho1 complete

        // ---- publish VALID h tiles to LLC, then flag ----
        if (k < SEQ + 1) {
            if (tid < 128) {
                int t2 = tid & 63;
                int r = t2 >> 2, c4 = (t2 & 3) * 4;          // 4 shorts = 1 u64
                bool isH0 = (tid < 64);
                // ho0 valid only when L0 ran (k<SEQ); ho1 only when L1 ran (k>=1)
                bool valid = isH0 ? (k < SEQ) : (k >= 1);
                if (valid) {
                    u64* dst = isH0 ? h0c : h1c;
                    const short* srcrow = isH0 ? &ho0[r][c4] : &ho1[r][c4];
                    u64 v = *(const u64*)srcrow;
                    sys_store_u64(dst + (bg * 16 + r) * 64 + (colbase >> 2) + (t2 & 3), v);
                }
            }
            __syncthreads();   // drains vmcnt(0) for ALL waves before s_barrier
            if (tid == 0) sys_store_u32(&flags[j * 16], (unsigned)(k + 1));
        }
    }
}

extern "C" void kernel_launch(void* const* d_in, const int* in_sizes, int n_in,
                              void* d_out, int out_size, void* d_ws, size_t ws_size,
                              hipStream_t stream) {
    const float* z     = (const float*)d_in[0];
    const float* Whid  = (const float*)d_in[1];
    const float* bhid  = (const float*)d_in[2];
    const float* Wcell = (const float*)d_in[3];
    const float* bcell = (const float*)d_in[4];
    const float* Win   = (const float*)d_in[5];
    const float* bin   = (const float*)d_in[6];
    const float* Wih0  = (const float*)d_in[7];
    const float* Whh0  = (const float*)d_in[8];
    const float* bih0  = (const float*)d_in[9];
    const float* bhh0  = (const float*)d_in[10];
    const float* Wih1  = (const float*)d_in[11];
    const float* Whh1  = (const float*)d_in[12];
    const float* bih1  = (const float*)d_in[13];
    const float* bhh1  = (const float*)d_in[14];
    const float* Wout  = (const float*)d_in[15];
    const float* bout  = (const float*)d_in[16];
    float* out = (float*)d_out;

    // workspace carve-up (~2.3 MB)
    float* gxb0 = (float*)d_ws;                  // [256][1024]
    float* gxb1 = gxb0 + 262144;                 // [1024]
    float* c0   = gxb1 + 1024;                   // [256][256]
    float* c1   = c0 + 65536;                    // [256][256]
    float* x0   = c1 + 65536;                    // [256][256]
    __hip_bfloat16* h0b0 = (__hip_bfloat16*)(x0 + 65536);   // [256][256] bf16 x4
    __hip_bfloat16* h0b1 = h0b0 + 65536;
    __hip_bfloat16* h1b0 = h0b1 + 65536;
    __hip_bfloat16* h1b1 = h1b0 + 65536;
    unsigned* bar = (unsigned*)(h1b1 + 65536);   // [4096] barrier flags

    lstm_prologue_init<<<1300, 256, 0, stream>>>(z, Whid, bhid, Wcell, bcell, Win, bin,
                                                 bih1, bhh1, h0b1, h1b1, c0, c1, x0, gxb1, bar);
    lstm_prologue_gx0<<<dim3(4, 256), 256, 0, stream>>>(x0, Wih0, bih0, bhh0, gxb0);

    u64* h0b0u = (u64*)h0b0; u64* h0b1u = (u64*)h0b1;
    u64* h1b0u = (u64*)h1b0; u64* h1b1u = (u64*)h1b1;
    void* kargs[] = { (void*)&gxb0, (void*)&gxb1, (void*)&c0, (void*)&c1,
                      (void*)&h0b0u, (void*)&h0b1u, (void*)&h1b0u, (void*)&h1b1u,
                      (void*)&Whh0, (void*)&Wih1, (void*)&Whh1, (void*)&Wout,
                      (void*)&bout, (void*)&out, (void*)&bar };
    hipLaunchCooperativeKernel((const void*)lstm_persistent, dim3(256), dim3(256),
                               kargs, 0, stream);
}

// Round 8
// 1984.455 us; speedup vs baseline: 14.9988x; 1.1844x over previous
//
#include <hip/hip_runtime.h>
#include <hip/hip_bf16.h>

#define LAT 128
#define H 256
#define OUTD 64
#define SEQ 512

typedef short bf16x8 __attribute__((ext_vector_type(8)));
typedef float f32x4  __attribute__((ext_vector_type(4)));
typedef unsigned long long u64;
typedef unsigned u32;

__device__ __forceinline__ float sigm(float x)  { return 1.f / (1.f + __expf(-x)); }
__device__ __forceinline__ float tanhf_(float x){ return 1.f - 2.f / (__expf(2.f * x) + 1.f); }

__device__ __forceinline__ short f2bs(float x) {
    __hip_bfloat16 b = __float2bfloat16(x);
    return *reinterpret_cast<short*>(&b);
}
__device__ __forceinline__ float bs2f(unsigned short h) {
    u32 b = ((u32)h) << 16;
    float f; __builtin_memcpy(&f, &b, 4); return f;
}
__device__ __forceinline__ u32 f2pair(float a, float b) {
    return ((u32)(unsigned short)f2bs(b) << 16) | (u32)(unsigned short)f2bs(a);
}
__device__ __forceinline__ bf16x8 pack8(const float* s) {
    bf16x8 v;
    v[0]=f2bs(s[0]); v[1]=f2bs(s[1]); v[2]=f2bs(s[2]); v[3]=f2bs(s[3]);
    v[4]=f2bs(s[4]); v[5]=f2bs(s[5]); v[6]=f2bs(s[6]); v[7]=f2bs(s[7]);
    return v;
}

// ---- LLC-direct coherent accessors (round-5-proven transport) ----
__device__ __forceinline__ u64 sys_load_u64(const u64* p) {
    return __hip_atomic_load((u64*)p, __ATOMIC_RELAXED, __HIP_MEMORY_SCOPE_SYSTEM);
}
__device__ __forceinline__ void sys_store_u64(u64* p, u64 v) {
    __hip_atomic_store(p, v, __ATOMIC_RELAXED, __HIP_MEMORY_SCOPE_SYSTEM);
}

// ---------------- Prologue 1: tagged h-init, c-init, layer-1 bias ----------------
// Tagged h slot: u64 = (tag << 32) | (bf16[col+1] << 16) | bf16[col].
// h0 init -> h0B1 tag 0 (consumed at iter 0); h1 init -> h1B1 tag 1 (iter 1).
__global__ void lstm_prologue_init(const float* __restrict__ z,
                                   const float* __restrict__ Whid,
                                   const float* __restrict__ bhid,
                                   const float* __restrict__ Wcell,
                                   const float* __restrict__ bcell,
                                   const float* __restrict__ bih1,
                                   const float* __restrict__ bhh1,
                                   u64* __restrict__ h0B1,
                                   u64* __restrict__ h1B1,
                                   float* __restrict__ c0,
                                   float* __restrict__ c1,
                                   float* __restrict__ gxb1)
{
    int t = blockIdx.x * 256 + threadIdx.x;
    if (t < 65536) {                     // tagged hidden-init: 2 layers x 256 b x 128 pairs
        int layer = t >> 15;
        int tt = t & 32767;
        int b = tt >> 7, cp = tt & 127;
        int colA = layer * H + 2 * cp;
        const float* zr = z + b * LAT;
        const float* wA = Whid + colA * LAT;
        const float* wB = wA + LAT;
        float a0 = bhid[colA], a1 = bhid[colA + 1];
        for (int k = 0; k < LAT; k++) { float zv = zr[k]; a0 += zv * wA[k]; a1 += zv * wB[k]; }
        u64 v = ((u64)(u32)layer << 32) | (u64)f2pair(a0, a1);
        (layer ? h1B1 : h0B1)[b * 128 + cp] = v;
    } else if (t < 196608) {             // cell init: [256 x 512]
        int tt = t - 65536;
        int b = tt >> 9, col = tt & 511;
        const float* w  = Wcell + col * LAT;
        const float* zr = z + b * LAT;
        float acc = bcell[col];
        for (int k = 0; k < LAT; k++) acc += zr[k] * w[k];
        if (col < H) c0[b * H + col] = acc;
        else         c1[b * H + (col - H)] = acc;
    } else if (t < 197632) {             // layer-1 gate bias vector [1024]
        int g = t - 196608;
        gxb1[g] = bih1[g] + bhh1[g];
    }
}

// ---------------- Prologue 2: gx0 = (z@Win.T+bin) @ W_ih0.T + biases, bf16 pairs ----------------
// grid (2, 256): block covers 512 gate-cols of batch row b; thread -> 2 cols.
__global__ void lstm_prologue_gx0(const float* __restrict__ z,
                                  const float* __restrict__ Win,
                                  const float* __restrict__ bin,
                                  const float* __restrict__ Wih0,
                                  const float* __restrict__ bih0,
                                  const float* __restrict__ bhh0,
                                  u32* __restrict__ gxb0u)
{
    __shared__ float xs[H];
    const int b = blockIdx.y;
    const int tid = threadIdx.x;
    {
        const float* w  = Win + tid * LAT;
        const float* zr = z + b * LAT;
        float acc = bin[tid];
        for (int k = 0; k < LAT; k++) acc += zr[k] * w[k];
        xs[tid] = acc;
    }
    __syncthreads();
    const int cA = blockIdx.x * 512 + 2 * tid;
    const float* wA = Wih0 + cA * H;
    const float* wB = wA + H;
    float a0 = bih0[cA]     + bhh0[cA];
    float a1 = bih0[cA + 1] + bhh0[cA + 1];
    for (int k = 0; k < H; k++) { float xv = xs[k]; a0 += xv * wA[k]; a1 += xv * wB[k]; }
    gxb0u[b * 512 + blockIdx.x * 256 + tid] = f2pair(a0, a1);
}

// ---------------- Persistent kernel ----------------
// 256 wgs x 256 thr. blockIdx clustering: bg = wg>>4 (batch rows 16bg..),
// j = wg&15 (16 gate cols). Tagged u64 slots, SYSTEM scope: the staging poll
// IS the synchronization. Tag published at iter k is k+1; staging at iter k
// polls tag==k. Producers can't overwrite tag k with k+2 until every peer
// consumed k (their own staging blocks on it) — race-free.
__global__ __launch_bounds__(256, 1)
void lstm_persistent(const u32* __restrict__ gxb0u, const float* __restrict__ gxb1,
                     const float* __restrict__ c0g, const float* __restrict__ c1g,
                     u64* __restrict__ h0B0, u64* __restrict__ h0B1,
                     u64* __restrict__ h1B0, u64* __restrict__ h1B1,
                     const float* __restrict__ Whh0, const float* __restrict__ Wih1,
                     const float* __restrict__ Whh1, const float* __restrict__ Wout,
                     const float* __restrict__ bout, float* __restrict__ out)
{
    const int wg = blockIdx.x;
    const int bg = wg >> 4;
    const int j  = wg & 15;
    const int colbase = j * 16;
    const int tid  = threadIdx.x;
    const int wave = tid >> 6;
    const int lane = tid & 63;
    const int q  = lane >> 4;
    const int ln = lane & 15;
    const int m_ = tid >> 4, n_ = tid & 15;

    __shared__ u32 hsu0[16 * 132];             // h0_prev: 16 rows x 128 pairs (+4 pad)
    __shared__ u32 hsu1[16 * 132];             // h1_prev
    __shared__ float sm[4][16][17];            // gate exchange
    __shared__ float gx0s[4][16][17];          // L0 input-proj slice (constant)
    __shared__ float gx1s[4][17];              // L1 bias slice (constant)
    __shared__ short ho0[16][18];              // h0 output tile
    __shared__ short ho1[16][18];              // h1 output tile

    // ---- register-resident weight B-fragments ----
    bf16x8 wf[3][8];
    {
        const float* mats[3] = { Whh0, Wih1, Whh1 };
        const int row = wave * H + colbase + ln;
        #pragma unroll
        for (int mm = 0; mm < 3; mm++) {
            const float* src = mats[mm] + row * H + q * 8;
            #pragma unroll
            for (int kk = 0; kk < 8; kk++) wf[mm][kk] = pack8(src + kk * 32);
        }
    }
    const bool doOut = (j < 4) && (wave == 0);
    bf16x8 wo[8];
    float bo = 0.f;
    if (doOut) {
        const int orow = j * 16 + ln;
        const float* src = Wout + orow * H + q * 8;
        #pragma unroll
        for (int kk = 0; kk < 8; kk++) wo[kk] = pack8(src + kk * 32);
        bo = bout[orow];
    }

    // ---- constant LDS preloads (gx0 from packed bf16 pairs) ----
    for (int idx = tid; idx < 512; idx += 256) {
        int g = idx >> 7, rem = idx & 127;
        int m = rem >> 3, pp = rem & 7;
        u32 v = gxb0u[(bg * 16 + m) * 512 + g * 128 + j * 8 + pp];
        gx0s[g][m][2 * pp]     = bs2f((unsigned short)(v & 0xFFFFu));
        gx0s[g][m][2 * pp + 1] = bs2f((unsigned short)(v >> 16));
    }
    if (tid < 64) gx1s[tid >> 4][tid & 15] = gxb1[(tid >> 4) * H + colbase + (tid & 15)];

    // ---- cell state in registers ----
    const int cidx = (bg * 16 + m_) * H + colbase + n_;
    float creg0 = c0g[cidx];
    float creg1 = c1g[cidx];

    u64* a0 = h0B0 + bg * 2048;   // cluster slices: 16 rows x 128 pair-slots
    u64* a1 = h0B1 + bg * 2048;
    u64* b0 = h1B0 + bg * 2048;
    u64* b1 = h1B1 + bg * 2048;

    const short* hp0 = (const short*)hsu0;
    const short* hp1 = (const short*)hsu1;

    for (int k = 0; k <= SEQ + 1; k++) {
        const u64* p0 = (k & 1) ? a0 : a1;     // h0_{k-1} (tag k)
        u64*      c0p = (k & 1) ? a1 : a0;     // h0_k     (tag k+1)
        const u64* p1 = (k & 1) ? b1 : b0;     // h1_{k-2} (tag k)
        u64*      c1p = (k & 1) ? b0 : b1;     // h1_{k-1} (tag k+1)

        // ---- tag-polled staging: the poll IS the synchronization ----
        {
            const bool w0 = (k <= SEQ);        // h0 unused at k=SEQ+1
            const bool w1 = (k >= 1);          // h1 unused at k=0
            u64 v0[8], v1[8];
            unsigned pend0 = w0 ? 0xFFu : 0u;
            unsigned pend1 = w1 ? 0xFFu : 0u;
            #pragma unroll
            for (int i = 0; i < 8; i++) if (w0) v0[i] = sys_load_u64(p0 + i * 256 + tid);
            #pragma unroll
            for (int i = 0; i < 8; i++) if (w1) v1[i] = sys_load_u64(p1 + i * 256 + tid);
            int guard = 0;
            while (pend0 | pend1) {
                unsigned np0 = 0u, np1 = 0u;
                #pragma unroll
                for (int i = 0; i < 8; i++) if ((pend0 >> i) & 1u) {
                    if ((u32)(v0[i] >> 32) != (u32)k) { v0[i] = sys_load_u64(p0 + i * 256 + tid); np0 |= 1u << i; }
                }
                #pragma unroll
                for (int i = 0; i < 8; i++) if ((pend1 >> i) & 1u) {
                    if ((u32)(v1[i] >> 32) != (u32)k) { v1[i] = sys_load_u64(p1 + i * 256 + tid); np1 |= 1u << i; }
                }
                pend0 = np0; pend1 = np1;
                if (++guard > 32768) break;    // fail fast instead of hanging
            }
            #pragma unroll
            for (int i = 0; i < 8; i++) if (w0) { int s = i * 256 + tid; hsu0[(s >> 7) * 132 + (s & 127)] = (u32)v0[i]; }
            #pragma unroll
            for (int i = 0; i < 8; i++) if (w1) { int s = i * 256 + tid; hsu1[(s >> 7) * 132 + (s & 127)] = (u32)v1[i]; }
        }
        __syncthreads();                       // B1

        // ---- A-fragments (shared by L0, L1, out) ----
        bf16x8 ha0[8], ha1[8];
        #pragma unroll
        for (int kk = 0; kk < 8; kk++) {
            ha0[kk] = *(const bf16x8*)&hp0[ln * 264 + kk * 32 + q * 8];
            ha1[kk] = *(const bf16x8*)&hp1[ln * 264 + kk * 32 + q * 8];
        }

        // ---- layer 0, step k ----
        if (k < SEQ) {
            f32x4 acc = {0.f, 0.f, 0.f, 0.f};
            #pragma unroll
            for (int kk = 0; kk < 8; kk++)
                acc = __builtin_amdgcn_mfma_f32_16x16x32_bf16(ha0[kk], wf[0][kk], acc, 0, 0, 0);
            #pragma unroll
            for (int r = 0; r < 4; r++)
                sm[wave][q * 4 + r][ln] = acc[r] + gx0s[wave][q * 4 + r][ln];
        }
        __syncthreads();                       // B2
        if (k < SEQ) {
            float xi = sm[0][m_][n_], xf = sm[1][m_][n_], xg = sm[2][m_][n_], xo = sm[3][m_][n_];
            float c = sigm(xf) * creg0 + sigm(xi) * tanhf_(xg);
            creg0 = c;
            ho0[m_][n_] = f2bs(sigm(xo) * tanhf_(c));
        }
        __syncthreads();                       // B3 (sm free + ho0 ready)

        // ---- early h0 publish (tag k+1): commit overlaps L1 compute ----
        if (k < SEQ && tid < 128) {
            int r = tid >> 3, p = tid & 7;
            u32 pa = ((u32)(unsigned short)ho0[r][2 * p + 1] << 16) | (u32)(unsigned short)ho0[r][2 * p];
            sys_store_u64(c0p + r * 128 + j * 8 + p, ((u64)(u32)(k + 1) << 32) | (u64)pa);
        }

        // ---- layer 1, step k-1 ----
        if (k >= 1 && k <= SEQ) {
            f32x4 acc = {0.f, 0.f, 0.f, 0.f};
            #pragma unroll
            for (int kk = 0; kk < 8; kk++)
                acc = __builtin_amdgcn_mfma_f32_16x16x32_bf16(ha0[kk], wf[1][kk], acc, 0, 0, 0);
            #pragma unroll
            for (int kk = 0; kk < 8; kk++)
                acc = __builtin_amdgcn_mfma_f32_16x16x32_bf16(ha1[kk], wf[2][kk], acc, 0, 0, 0);
            #pragma unroll
            for (int r = 0; r < 4; r++)
                sm[wave][q * 4 + r][ln] = acc[r] + gx1s[wave][ln];
        }
        __syncthreads();                       // B4
        if (k >= 1 && k <= SEQ) {
            float xi = sm[0][m_][n_], xf = sm[1][m_][n_], xg = sm[2][m_][n_], xo = sm[3][m_][n_];
            float c = sigm(xf) * creg1 + sigm(xi) * tanhf_(xg);
            creg1 = c;
            ho1[m_][n_] = f2bs(sigm(xo) * tanhf_(c));
        }
        __syncthreads();                       // B5 (ho1 ready)

        // ---- h1 publish (tag k+1) ----
        if (k >= 1 && k <= SEQ && tid < 128) {
            int r = tid >> 3, p = tid & 7;
            u32 pa = ((u32)(unsigned short)ho1[r][2 * p + 1] << 16) | (u32)(unsigned short)ho1[r][2 * p];
            sys_store_u64(c1p + r * 128 + j * 8 + p, ((u64)(u32)(k + 1) << 32) | (u64)pa);
        }

        // ---- output projection, step k-2 (reuses ha1 = h1_{k-2}) ----
        if (k >= 2 && doOut) {
            f32x4 acc = {0.f, 0.f, 0.f, 0.f};
            #pragma unroll
            for (int kk = 0; kk < 8; kk++)
                acc = __builtin_amdgcn_mfma_f32_16x16x32_bf16(ha1[kk], wo[kk], acc, 0, 0, 0);
            const int t = k - 2;
            #pragma unroll
            for (int r = 0; r < 4; r++)
                out[(bg * 16 + q * 4 + r) * (SEQ * OUTD) + t * OUTD + j * 16 + ln] = acc[r] + bo;
        }
        // next iteration's hsu writes happen after B5; all hsu/sm/ho reads of
        // this iteration completed before B5 — no trailing barrier needed.
    }
}

extern "C" void kernel_launch(void* const* d_in, const int* in_sizes, int n_in,
                              void* d_out, int out_size, void* d_ws, size_t ws_size,
                              hipStream_t stream) {
    const float* z     = (const float*)d_in[0];
    const float* Whid  = (const float*)d_in[1];
    const float* bhid  = (const float*)d_in[2];
    const float* Wcell = (const float*)d_in[3];
    const float* bcell = (const float*)d_in[4];
    const float* Win   = (const float*)d_in[5];
    const float* bin   = (const float*)d_in[6];
    const float* Wih0  = (const float*)d_in[7];
    const float* Whh0  = (const float*)d_in[8];
    const float* bih0  = (const float*)d_in[9];
    const float* bhh0  = (const float*)d_in[10];
    const float* Wih1  = (const float*)d_in[11];
    const float* Whh1  = (const float*)d_in[12];
    const float* bih1  = (const float*)d_in[13];
    const float* bhh1  = (const float*)d_in[14];
    const float* Wout  = (const float*)d_in[15];
    const float* bout  = (const float*)d_in[16];
    float* out = (float*)d_out;

    // workspace carve-up: 2,101,248 B total (< round-5-proven 2,379,776 B)
    u32*   gxb0u = (u32*)d_ws;                   // [131072] bf16-pair slots
    float* gxb1  = (float*)(gxb0u + 131072);     // [1024]
    float* c0    = gxb1 + 1024;                  // [65536]
    float* c1    = c0 + 65536;                   // [65536]
    u64*   h0B0  = (u64*)(c1 + 65536);           // [32768] tagged pair-slots x4
    u64*   h0B1  = h0B0 + 32768;
    u64*   h1B0  = h0B1 + 32768;
    u64*   h1B1  = h1B0 + 32768;

    lstm_prologue_init<<<772, 256, 0, stream>>>(z, Whid, bhid, Wcell, bcell,
                                                bih1, bhh1, h0B1, h1B1, c0, c1, gxb1);
    lstm_prologue_gx0<<<dim3(2, 256), 256, 0, stream>>>(z, Win, bin, Wih0, bih0, bhh0, gxb0u);

    void* kargs[] = { (void*)&gxb0u, (void*)&gxb1, (void*)&c0, (void*)&c1,
                      (void*)&h0B0, (void*)&h0B1, (void*)&h1B0, (void*)&h1B1,
                      (void*)&Whh0, (void*)&Wih1, (void*)&Whh1, (void*)&Wout,
                      (void*)&bout, (void*)&out };
    hipError_t ce = hipLaunchCooperativeKernel((const void*)lstm_persistent,
                                               dim3(256), dim3(256), kargs, 0, stream);
    if (ce != hipSuccess) {
        // occupancy/validation rejection: plain launch (256 blocks @ 1 wg/CU are
        // co-resident on an idle device; staging guards prevent hangs regardless)
        lstm_persistent<<<256, 256, 0, stream>>>(gxb0u, gxb1, c0, c1,
                                                 h0B0, h0B1, h1B0, h1B1,
                                                 Whh0, Wih1, Whh1, Wout, bout, out);
    }
}